// Round 3
// baseline (975.239 us; speedup 1.0000x reference)
//
#include <hip/hip_runtime.h>

// Problem shape (fixed by the reference): x[B,D] fp32, L[V,D] fp32,
// target[B] int, class_weight[V] fp32 -> scalar fp32 loss.
#define B_ 4096
#define D_ 2048
#define V_ 32000

// R9: A-DIRECT. R7/R8 post-mortem: two schedule-surgery rounds gave +7%/+2%;
// counters show MFMA (2212cy) and LDS (2800cy) pipes still fully SERIAL per
// tile (MfmaUtil 39% = 2212/5680). Fix is structural, not scheduling: the
// A-operand is 128KB of the 192KB LDS reads/tile (4x wave_n redundancy) but
// x is 8.4MB -> L2/L3-resident and re-read 125x across col-blocks. So: load
// A fragments DIRECTLY global->register (flatmm pattern for the cached
// operand); keep only B (HBM-streamed) in double-buffered swizzled LDS.
//   - LDS/tile: 2800 -> ~1000cy  (< MFMA 2212cy => hideable with no tricks)
//   - LDS footprint 128 -> 64 KiB; ONE barrier per tile
//   - A-loads pipeline via ordinary vmcnt scoreboarding, never barrier-aligned
#define BM 256
#define BN 256
#define BKB 128              // K-tile depth in BYTES (fp8: 128 elements)
#define NT (D_ / BKB)        // 16 K-tiles
#define NCHUNK (V_ / 64)     // 500 per-row (max,sumexp) partials, one per 64-col wave tile

typedef __attribute__((ext_vector_type(8))) int   int8v;   // 8 dwords = fp8 A/B frag
typedef __attribute__((ext_vector_type(4))) int   int4v;
typedef __attribute__((ext_vector_type(4))) float f32x4;

// e8m0 scales: value = 2^(byte-127). x quantized as-is -> scale 2^0 = 127.
// L quantized as L*2^6 (lifts ~0.02-magnitude entries out of e4m3 subnormal
// range) -> scale 2^-6 = 121. Uniform scales => scale-lane mapping irrelevant.
#define SCALE_A 127
#define SCALE_B 121

// ---------------------------------------------------------------- helpers ---
__device__ __forceinline__ void load_lds16(const void* g, void* l) {
    // async global->LDS, 16B per lane; LDS dest must be wave-uniform base + lane*16
    __builtin_amdgcn_global_load_lds(
        (const __attribute__((address_space(1))) void*)g,
        (__attribute__((address_space(3))) void*)l,
        16, 0, 0);
}

// B fragment from swizzled LDS (two 16B chunks at positions quad^swz, (quad+4)^swz)
__device__ __forceinline__ int8v frag(const unsigned char* buf, int base, int p0, int p1) {
    union { int8v v8; int4v v4[2]; } u;
    u.v4[0] = *(const int4v*)(buf + base + p0);
    u.v4[1] = *(const int4v*)(buf + base + p1);
    return u.v8;
}

// A fragment direct from global: k-bytes [quad*16,+16) and [64+quad*16,+16)
// -- the SAME global k-chunks the swizzled-LDS B read yields (chunk map
// c(quad,h)=quad+4h), so the A/B k-permutation stays identical (uniform e8m0
// scales => permutation invisible to the math).
__device__ __forceinline__ int8v gfrag(const unsigned char* p) {
    union { int8v v8; int4v v4[2]; } u;
    u.v4[0] = *(const int4v*)(p);
    u.v4[1] = *(const int4v*)(p + 64);
    return u.v8;
}

// ------------------------------------------------------------ cast kernel ---
// Fused x + L cast, 4 floats -> 4 fp8 bytes per thread. Grid-stride with a
// capped grid (G11): the old 71,750-block launch is the prime suspect for the
// ~350us of non-gemm time that never shows in top-5 dispatches.
__global__ void cast_f32_to_fp8(const float* __restrict__ x,
                                const float* __restrict__ L,
                                unsigned int* __restrict__ xq,
                                unsigned int* __restrict__ Lq) {
    const int n4x = (B_ * D_) / 4;
    const int n4l = (V_ * D_) / 4;
    const int total = n4x + n4l;
    const int stride = gridDim.x * blockDim.x;
    for (int i = blockIdx.x * blockDim.x + threadIdx.x; i < total; i += stride) {
        const float* in; unsigned int* out; float ps; int j;
        if (i < n4x) { in = x; out = xq; ps = 1.0f;  j = i; }
        else         { in = L; out = Lq; ps = 64.0f; j = i - n4x; }
        float4 v = ((const float4*)in)[j];
        int w = __builtin_amdgcn_cvt_pk_fp8_f32(v.x * ps, v.y * ps, 0, false);
        w     = __builtin_amdgcn_cvt_pk_fp8_f32(v.z * ps, v.w * ps, w, true);
        out[j] = (unsigned)w;
    }
}

// ------------------------------------------------- GEMM + online-softmax ----
// MX-fp8 path: mfma_scale_f32_16x16x128_f8f6f4 (K=128/instr). 256x256 tile,
// 8 waves (2M x 4N), wave tile 128x64.
//
// B LDS: XOR-swizzled 16B chunks (8 chunks/row of 128B). Row r stores global
// chunk c at position c^(r&7), via pre-swizzled global source addresses
// (global_load_lds destination must stay linear lane*16). Read pattern
// measured 0 bank conflicts. Double-buffered: 2 x 32 KB.
//
// Per-tile flow (ONE barrier):
//   b0..b3 <- 8 ds_read_b128 (Bs[cur])
//   stage B(t+1) -> Bs[nxt]       (4 global_load_lds, issued FIRST)
//   a0..a3 <- 8 global dwordx4    (L2-hot x)
//   16 MFMA (mi0-3 x ni0-3)       [waits on a0-3 retire staging via FIFO]
//   a4..a7 <- 8 global dwordx4    (issue overlaps MFMA pipe, ~550cy cover)
//   16 MFMA (mi4-7)
//   s_waitcnt vmcnt(0)            (belt: ~free, everything already retired)
//   s_barrier
// Register budget: acc 128 + b 32 + a(two batches of 4) ~32 + addr ~20
// => ~215/wave, under the 256 cliff (2 waves/SIMD).
__global__ __launch_bounds__(512, 2)
void gemm_ce_partials(const unsigned char* __restrict__ xq,   // [B_,D_] fp8
                      const unsigned char* __restrict__ Lq,   // [V_,D_] fp8 (x2^6)
                      const int* __restrict__ targ,           // [B_]
                      float2* __restrict__ partials,          // [B_][NCHUNK]
                      float* __restrict__ gathered) {         // [B_] logit@target
    __shared__ __align__(16) unsigned char Bs[2][BN * BKB];   // 2 x 32 KB

    const int tid    = threadIdx.x;
    const int lane   = tid & 63;
    const int wid    = tid >> 6;         // 0..7
    const int wave_m = wid >> 2;         // 0..1  (row half: 128 rows)
    const int wave_n = wid & 3;          // 0..3  (col quarter: 64 cols)
    const int quad   = lane >> 4;        // 0..3
    const int l16    = lane & 15;
    const int swz    = l16 & 7;          // read-side XOR key (row&7 == l16&7)

    const int m0 = blockIdx.x * BM;      // row-block: FAST dim
    const int n0 = blockIdx.y * BN;      // col-block: SLOW dim

    // B staging geometry: pass p covers rows p*64..p*64+63 of the col-block.
    // row = p*64 + (tid>>3); pc = tid&7; global chunk c = pc^(row&7)
    // (p-invariant since 64%8==0). Linear in p: src += p*64*D_, dst += p*8K.
    const int r0 = tid >> 3;
    const int c0 = (tid & 7) ^ (r0 & 7);
    const unsigned char* sB = Lq + (size_t)(n0 + r0) * D_ + c0 * 16;
    const int d0 = tid * 16;
#define STEP (64 * D_)       // global row stride per pass
#define DSTEP 8192           // LDS byte stride per pass

    // A direct-load base: lane reads row (wave_m*128 + mi*16 + l16), k-chunk
    // bytes quad*16 and 64+quad*16 within the tile's 128B k-window.
    const unsigned char* pA =
        xq + (size_t)(m0 + wave_m * 128 + l16) * D_ + (quad << 4);
#define AOFF(mi) ((size_t)(mi) * 16 * D_)

    f32x4 acc[8][4];
#pragma unroll
    for (int i = 0; i < 8; ++i)
#pragma unroll
        for (int j = 0; j < 4; ++j)
            acc[i][j] = (f32x4){0.f, 0.f, 0.f, 0.f};

    // swizzled byte offsets of this lane's two 16B B-chunks
    const int p0 = ((quad ^ swz) << 4);
    const int p1 = p0 ^ 64;              // ((quad+4)^swz)<<4

    const int brow = (wave_n * 64 + l16) * BKB;
#define BB(ni) (brow + (ni) * (16 * BKB))
#define MM(A, B, MI, NI)                                                     \
    acc[MI][NI] = __builtin_amdgcn_mfma_scale_f32_16x16x128_f8f6f4(          \
        A, B, acc[MI][NI], 0, 0, 0, SCALE_A, 0, SCALE_B)

    // ---- prologue: stage B K-tile 0 into buffer 0, full drain once --------
#pragma unroll
    for (int p = 0; p < 4; ++p)
        load_lds16(sB + (size_t)p * STEP, &Bs[0][d0 + p * DSTEP]);
    asm volatile("s_waitcnt vmcnt(0)" ::: "memory");
    __builtin_amdgcn_s_barrier();

    for (int kt = 0; kt < NT; ++kt) {
        const int cur = kt & 1;
        const int nxt = cur ^ 1;
        const size_t kk = (size_t)kt * BKB;          // this tile's k-offset
        const size_t k1 = kk + BKB;                  // prefetch k-offset
        const bool pf = (kt + 1 < NT);
        const unsigned char* Bc = Bs[cur];

        // B fragments from swizzled LDS (8 x ds_read_b128, zero conflicts)
        int8v b0 = frag(Bc, BB(0), p0, p1);
        int8v b1 = frag(Bc, BB(1), p0, p1);
        int8v b2 = frag(Bc, BB(2), p0, p1);
        int8v b3 = frag(Bc, BB(3), p0, p1);

        // stage B(t+1) FIRST (FIFO: any later a-load wait retires these too)
        if (pf) {
#pragma unroll
            for (int p = 0; p < 4; ++p)
                load_lds16(sB + k1 + (size_t)p * STEP, &Bs[nxt][d0 + p * DSTEP]);
        }

        // A fragments, first half (global, L2-hot)
        int8v a0 = gfrag(pA + kk + AOFF(0));
        int8v a1 = gfrag(pA + kk + AOFF(1));
        int8v a2 = gfrag(pA + kk + AOFF(2));
        int8v a3 = gfrag(pA + kk + AOFF(3));

        __builtin_amdgcn_s_setprio(1);
        MM(a0, b0, 0, 0); MM(a0, b1, 0, 1); MM(a0, b2, 0, 2); MM(a0, b3, 0, 3);
        MM(a1, b0, 1, 0); MM(a1, b1, 1, 1); MM(a1, b2, 1, 2); MM(a1, b3, 1, 3);
        MM(a2, b0, 2, 0); MM(a2, b1, 2, 1); MM(a2, b2, 2, 2); MM(a2, b3, 2, 3);
        MM(a3, b0, 3, 0); MM(a3, b1, 3, 1); MM(a3, b2, 3, 2); MM(a3, b3, 3, 3);
        __builtin_amdgcn_s_setprio(0);

        // A fragments, second half (issue overlaps the MFMA pipe above)
        int8v a4 = gfrag(pA + kk + AOFF(4));
        int8v a5 = gfrag(pA + kk + AOFF(5));
        int8v a6 = gfrag(pA + kk + AOFF(6));
        int8v a7 = gfrag(pA + kk + AOFF(7));

        __builtin_amdgcn_s_setprio(1);
        MM(a4, b0, 4, 0); MM(a4, b1, 4, 1); MM(a4, b2, 4, 2); MM(a4, b3, 4, 3);
        MM(a5, b0, 5, 0); MM(a5, b1, 5, 1); MM(a5, b2, 5, 2); MM(a5, b3, 5, 3);
        MM(a6, b0, 6, 0); MM(a6, b1, 6, 1); MM(a6, b2, 6, 2); MM(a6, b3, 6, 3);
        MM(a7, b0, 7, 0); MM(a7, b1, 7, 1); MM(a7, b2, 7, 2); MM(a7, b3, 7, 3);
        __builtin_amdgcn_s_setprio(0);

        // belt: staging for t+1 must be LDS-visible before any wave's next-tile
        // ds_reads. MFMA operand waits already retired it (FIFO) -> ~free.
        asm volatile("s_waitcnt vmcnt(0)" ::: "memory");
        __builtin_amdgcn_s_barrier();
    }

    // Epilogue. C layout (16x16): col = lane&15, row = quad*4 + reg.
    // Per wave: 128 rows (wave_m half, mi 0..7) x 64 cols (wave_n quarter).
    const int row_base = m0 + wave_m * 128;
    const int col_base = n0 + wave_n * 64;
    const int chunk    = blockIdx.y * 4 + wave_n;   // 0..499

    // hoist targ loads (latency overlaps the max/exp work below)
    int tv[32];
#pragma unroll
    for (int mi = 0; mi < 8; ++mi)
#pragma unroll
        for (int r = 0; r < 4; ++r)
            tv[mi * 4 + r] = targ[row_base + mi * 16 + quad * 4 + r];

    // wave-wide max M (valid shift for all 128 rows of this wave tile)
    float M = acc[0][0][0];
#pragma unroll
    for (int mi = 0; mi < 8; ++mi)
#pragma unroll
        for (int ni = 0; ni < 4; ++ni)
#pragma unroll
            for (int r = 0; r < 4; ++r)
                M = fmaxf(M, acc[mi][ni][r]);
#pragma unroll
    for (int off = 1; off < 64; off <<= 1)
        M = fmaxf(M, __shfl_xor(M, off, 64));

    // all exps first (independent), then flat shuffle rounds (32-way ILP)
    float sv[32];
#pragma unroll
    for (int mi = 0; mi < 8; ++mi)
#pragma unroll
        for (int r = 0; r < 4; ++r)
            sv[mi * 4 + r] = __expf(acc[mi][0][r] - M) + __expf(acc[mi][1][r] - M) +
                             __expf(acc[mi][2][r] - M) + __expf(acc[mi][3][r] - M);
#pragma unroll
    for (int off = 1; off < 16; off <<= 1)
#pragma unroll
        for (int i = 0; i < 32; ++i)
            sv[i] += __shfl_xor(sv[i], off, 64);

    if (l16 == 0) {
#pragma unroll
        for (int mi = 0; mi < 8; ++mi)
#pragma unroll
            for (int r = 0; r < 4; ++r) {
                int row = row_base + mi * 16 + quad * 4 + r;
                partials[(size_t)row * NCHUNK + chunk] = make_float2(M, sv[mi * 4 + r]);
            }
    }

    // target gather (rare hit: ~4096/32000 of (row, col-block) pairs)
#pragma unroll
    for (int mi = 0; mi < 8; ++mi)
#pragma unroll
        for (int r = 0; r < 4; ++r) {
            int row = row_base + mi * 16 + quad * 4 + r;
            int cb  = col_base + l16;
            int t   = tv[mi * 4 + r];
            if (cb      == t) gathered[row] = acc[mi][0][r];
            if (cb + 16 == t) gathered[row] = acc[mi][1][r];
            if (cb + 32 == t) gathered[row] = acc[mi][2][r];
            if (cb + 48 == t) gathered[row] = acc[mi][3][r];
        }
}

// ------------------------------------------------------ per-row combine -----
// one wave per row; block 256 -> 4 rows/block; grid B_/4
__global__ void combine_rows(const float2* __restrict__ partials,
                             const float* __restrict__ gathered,
                             const int* __restrict__ targ,
                             const float* __restrict__ cw,
                             float* __restrict__ row_loss,
                             float* __restrict__ row_w) {
    int row  = blockIdx.x * 4 + (threadIdx.x >> 6);
    int lane = threadIdx.x & 63;
    float m = -3.0e38f, s = 0.f;
    for (int c = lane; c < NCHUNK; c += 64) {
        float2 p = partials[(size_t)row * NCHUNK + c];
        float nm = fmaxf(m, p.x);
        s = s * __expf(m - nm) + p.y * __expf(p.x - nm);
        m = nm;
    }
#pragma unroll
    for (int off = 32; off; off >>= 1) {
        float om = __shfl_xor(m, off, 64);
        float os = __shfl_xor(s, off, 64);
        float nm = fmaxf(m, om);
        s = s * __expf(m - nm) + os * __expf(om - nm);
        m = nm;
    }
    if (lane == 0) {
        float logZ = m + __logf(s);
        int t = targ[row];
        bool valid = (t != -100);
        int ts = valid ? t : 0;
        float w = valid ? cw[ts] : 0.f;
        row_loss[row] = w * (logZ - gathered[row]);
        row_w[row]    = w;
    }
}

// ---------------------------------------------------------- final reduce ----
__global__ void final_reduce(const float* __restrict__ rl,
                             const float* __restrict__ rw,
                             float* __restrict__ out) {
    __shared__ float sl[4], sw[4];
    float a = 0.f, b = 0.f;
    for (int i = threadIdx.x; i < B_; i += 256) { a += rl[i]; b += rw[i]; }
#pragma unroll
    for (int off = 32; off; off >>= 1) {
        a += __shfl_xor(a, off, 64);
        b += __shfl_xor(b, off, 64);
    }
    int w = threadIdx.x >> 6;
    if ((threadIdx.x & 63) == 0) { sl[w] = a; sw[w] = b; }
    __syncthreads();
    if (threadIdx.x == 0) {
        float ta = sl[0] + sl[1] + sl[2] + sl[3];
        float tb = sw[0] + sw[1] + sw[2] + sw[3];
        out[0] = ta / tb;
    }
}

// ------------------------------------------------------------------ launch --
extern "C" void kernel_launch(void* const* d_in, const int* in_sizes, int n_in,
                              void* d_out, int out_size, void* d_ws, size_t ws_size,
                              hipStream_t stream) {
    const float* x  = (const float*)d_in[0];   // [B_,D_]
    const float* L  = (const float*)d_in[1];   // [V_,D_]
    const int* targ = (const int*)d_in[2];     // [B_]
    const float* cw = (const float*)d_in[3];   // [V_]
    float* out = (float*)d_out;

    // workspace carve-up (all 256B-aligned)
    char* ws = (char*)d_ws;
    size_t o = 0;
    unsigned char* xq = (unsigned char*)(ws + o);  o += (size_t)B_ * D_;         // 8.4 MB
    unsigned char* Lq = (unsigned char*)(ws + o);  o += (size_t)V_ * D_;         // 65.5 MB
    float2* partials = (float2*)(ws + o);          o += (size_t)B_ * NCHUNK * 8; // 16.4 MB
    float* gathered = (float*)(ws + o);            o += (size_t)B_ * 4;
    float* row_loss = (float*)(ws + o);            o += (size_t)B_ * 4;
    float* row_w    = (float*)(ws + o);            o += (size_t)B_ * 4;
    (void)ws_size;

    // 1) fused cast (x as-is; L pre-scaled 2^6, undone by MFMA e8m0 scale 2^-6)
    cast_f32_to_fp8<<<4096, 256, 0, stream>>>(x, L, (unsigned*)xq, (unsigned*)Lq);

    // 2) fused MX-fp8 GEMM + per-tile online softmax partials
    {
        dim3 grid(B_ / BM, V_ / BN);   // (16 fast, 125 slow) -- L2 locality
        gemm_ce_partials<<<grid, 512, 0, stream>>>(xq, Lq, targ, partials, gathered);
    }

    // 3) per-row combine
    combine_rows<<<B_ / 4, 256, 0, stream>>>(partials, gathered, targ, cw, row_loss, row_w);

    // 4) final scalar
    final_reduce<<<1, 256, 0, stream>>>(row_loss, row_w, out);
}

// Round 4
// 664.948 us; speedup vs baseline: 1.4666x; 1.4666x over previous
//
#include <hip/hip_runtime.h>

// Problem shape (fixed by the reference): x[B,D] fp32, L[V,D] fp32,
// target[B] int, class_weight[V] fp32 -> scalar fp32 loss.
#define B_ 4096
#define D_ 2048
#define V_ 32000

// R10: COUNTED-VMCNT CLUB STAGING. R9 (A-direct-global) was a disaster:
// 632us / 17% MfmaUtil -- per-lane 16B @ 2048B row stride = 64 cache lines
// per instr, 4x L2 amplification, MFMA waits became L2-latency chains.
// Reverted to R8's all-LDS structure (296us base).
// R8's remaining stall (per m218: counted-vs-drain0 = +38-73%): the per-tile
// s_waitcnt vmcnt(0) empties the VMEM queue every 2800cy. Fix requires each
// wave to certify ONLY ITS OWN staging loads (wait-own + barrier = collective
// certification). New staging geometry makes that exact:
//   A-half0 (tile rows 0-127) staged by + read by ONLY waves 0-3 (wave_m=0)
//   A-half1 by waves 4-7; B-half0 (cols 0-127) by waves {wave_n in 0,1} =
//   exactly its reader set; B-half1 likewise.
// Per tile each wave: 8 own-club staging loads. Boundary: issue 8 for t+1 ->
// s_waitcnt vmcnt(8) (drains t's, leaves t+1's in flight) -> s_barrier.
// NO zero-drain in the main loop; 2 barriers/tile; ds_reads+MFMA free-run
// under compiler per-operand lgkmcnt.
#define BM 256
#define BN 256
#define BKB 128              // K-tile depth in BYTES (fp8: 128 elements)
#define NT (D_ / BKB)        // 16 K-tiles
#define NCHUNK (V_ / 64)     // 500 per-row (max,sumexp) partials

typedef __attribute__((ext_vector_type(8))) int   int8v;   // 8 dwords = fp8 A/B frag
typedef __attribute__((ext_vector_type(4))) int   int4v;
typedef __attribute__((ext_vector_type(4))) float f32x4;

// e8m0 scales: value = 2^(byte-127). x quantized as-is -> scale 2^0 = 127.
// L quantized as L*2^6 (lifts ~0.02-magnitude entries out of e4m3 subnormal
// range) -> scale 2^-6 = 121. Uniform scales => scale-lane mapping irrelevant.
#define SCALE_A 127
#define SCALE_B 121

// ---------------------------------------------------------------- helpers ---
__device__ __forceinline__ void load_lds16(const void* g, void* l) {
    // async global->LDS, 16B per lane; LDS dest must be wave-uniform base + lane*16
    __builtin_amdgcn_global_load_lds(
        (const __attribute__((address_space(1))) void*)g,
        (__attribute__((address_space(3))) void*)l,
        16, 0, 0);
}

// fragment from swizzled LDS (two 16B chunks at positions quad^swz, (quad+4)^swz)
__device__ __forceinline__ int8v frag(const unsigned char* rowp, int p0, int p1) {
    union { int8v v8; int4v v4[2]; } u;
    u.v4[0] = *(const int4v*)(rowp + p0);
    u.v4[1] = *(const int4v*)(rowp + p1);
    return u.v8;
}

// ------------------------------------------------------------ cast kernel ---
// Fused x + L cast, 4 floats -> 4 fp8 bytes per thread, grid-stride.
__global__ void cast_f32_to_fp8(const float* __restrict__ x,
                                const float* __restrict__ L,
                                unsigned int* __restrict__ xq,
                                unsigned int* __restrict__ Lq) {
    const int n4x = (B_ * D_) / 4;
    const int n4l = (V_ * D_) / 4;
    const int total = n4x + n4l;
    const int stride = gridDim.x * blockDim.x;
    for (int i = blockIdx.x * blockDim.x + threadIdx.x; i < total; i += stride) {
        const float* in; unsigned int* out; float ps; int j;
        if (i < n4x) { in = x; out = xq; ps = 1.0f;  j = i; }
        else         { in = L; out = Lq; ps = 64.0f; j = i - n4x; }
        float4 v = ((const float4*)in)[j];
        int w = __builtin_amdgcn_cvt_pk_fp8_f32(v.x * ps, v.y * ps, 0, false);
        w     = __builtin_amdgcn_cvt_pk_fp8_f32(v.z * ps, v.w * ps, w, true);
        out[j] = (unsigned)w;
    }
}

// ------------------------------------------------- GEMM + online-softmax ----
// MX-fp8: mfma_scale_f32_16x16x128_f8f6f4. 256x256 tile, 8 waves (2M x 4N),
// wave tile 128x64. LDS layout per buffer (64 KB):
//   [0,16K)   A-half0 (tile rows 0-127)    club: waves 0-3
//   [16K,32K) A-half1 (tile rows 128-255)  club: waves 4-7
//   [32K,48K) B-half0 (tile cols 0-127)    club: waves {n=0,1} = {0,1,4,5}
//   [48K,64K) B-half1 (tile cols 128-255)  club: waves {n=2,3} = {2,3,6,7}
// Each half: 128 rows x 128B, XOR-swizzled 16B chunks (row r stores global
// chunk c at position c^(r&7); pre-swizzled global source, linear LDS dest).
// Frag reads (pos quad^swz / (quad+4)^swz) measured 0 bank conflicts; A and B
// get the identical k-chunk permutation (uniform e8m0 => invisible).
__global__ __launch_bounds__(512, 2)
void gemm_ce_partials(const unsigned char* __restrict__ xq,   // [B_,D_] fp8
                      const unsigned char* __restrict__ Lq,   // [V_,D_] fp8 (x2^6)
                      const int* __restrict__ targ,           // [B_]
                      float2* __restrict__ partials,          // [B_][NCHUNK]
                      float* __restrict__ gathered) {         // [B_] logit@target
    __shared__ __align__(16) unsigned char lds[2][65536];     // 128 KB

    const int tid    = threadIdx.x;
    const int lane   = tid & 63;
    const int wid    = tid >> 6;         // 0..7
    const int wave_m = wid >> 2;         // 0..1  (row half: 128 rows)
    const int wave_n = wid & 3;          // 0..3  (col quarter: 64 cols)
    const int quad   = lane >> 4;        // 0..3
    const int l16    = lane & 15;
    const int swz    = l16 & 7;          // read-side XOR key (row&7 == l16&7)

    const int m0 = blockIdx.x * BM;      // row-block: FAST dim
    const int n0 = blockIdx.y * BN;      // col-block: SLOW dim

    // ---- club staging geometry -------------------------------------------
    // A club (4 waves sharing wave_m): local wave idx cwA = wid&3.
    // B club (4 waves sharing h=wave_n>>1): local idx cwB = wave_m*2+(wave_n&1).
    // Thread's 4 chunks per operand: flat f = q*256 + cw*64 + lane, q=0..3.
    //   row (in half) = f>>3 = q*32 + cw*8 + (lane>>3); pos = f&7 = lane&7;
    //   global chunk c = (lane&7) ^ (row&7) = (lane&7) ^ (lane>>3)  [q,cw-inv].
    const int cwA = wid & 3;
    const int cwB = wave_m * 2 + (wave_n & 1);
    const int hB  = wave_n >> 1;
    const int lrow = lane >> 3;                    // 0..7
    const int cswz = (lane & 7) ^ lrow;            // staging chunk col
    const unsigned char* gA =
        xq + (size_t)(m0 + wave_m * 128 + cwA * 8 + lrow) * D_ + cswz * 16;
    const unsigned char* gB =
        Lq + (size_t)(n0 + hB * 128 + cwB * 8 + lrow) * D_ + cswz * 16;
    const int dA = wave_m * 16384 + (cwA * 64 + lane) * 16;          // + q*4096
    const int dB = 32768 + hB * 16384 + (cwB * 64 + lane) * 16;      // + q*4096
#define QSTEP ((size_t)32 * D_)   // 32 rows per q-pass

    // 8 staging loads per wave per tile, own clubs only.
#define STAGE(buf, koff) do {                                                  \
    _Pragma("unroll")                                                          \
    for (int q = 0; q < 4; ++q)                                                \
        load_lds16(gA + (koff) + (size_t)q * QSTEP, &lds[buf][dA + q * 4096]); \
    _Pragma("unroll")                                                          \
    for (int q = 0; q < 4; ++q)                                                \
        load_lds16(gB + (koff) + (size_t)q * QSTEP, &lds[buf][dB + q * 4096]); \
} while (0)

    f32x4 acc[8][4];
#pragma unroll
    for (int i = 0; i < 8; ++i)
#pragma unroll
        for (int j = 0; j < 4; ++j)
            acc[i][j] = (f32x4){0.f, 0.f, 0.f, 0.f};

    // swizzled byte offsets of a lane's two 16B chunks within its row
    const int p0 = ((quad ^ swz) << 4);
    const int p1 = p0 ^ 64;              // ((quad+4)^swz)<<4

    // frag-read bases (within current buffer)
    const int aoff = wave_m * 16384 + l16 * 128;                       // + mi*2048
    const int boff = 32768 + hB * 16384 + ((wave_n & 1) * 64 + l16) * 128; // + ni*2048

#define MM(A, B, MI, NI)                                                     \
    acc[MI][NI] = __builtin_amdgcn_mfma_scale_f32_16x16x128_f8f6f4(          \
        A, B, acc[MI][NI], 0, 0, 0, SCALE_A, 0, SCALE_B)

    // ---- prologue: stage K-tile 0 (no drain; certified at first boundary) --
    STAGE(0, 0);

    for (int kt = 0; kt < NT; ++kt) {
        const int cur = kt & 1;
        const int nxt = cur ^ 1;

        // boundary: issue t+1 staging, then certify OWN t-loads (counted!)
        if (kt + 1 < NT) {
            STAGE(nxt, (size_t)(kt + 1) * BKB);
            asm volatile("s_waitcnt vmcnt(8)" ::: "memory");  // t's 8 landed; t+1's in flight
        } else {
            asm volatile("s_waitcnt vmcnt(0)" ::: "memory");  // last tile: full drain
        }
        __builtin_amdgcn_s_barrier();    // collect all waves' certifications

        const unsigned char* Ac = &lds[cur][aoff];
        const unsigned char* Bc = &lds[cur][boff];

        // fragments + MFMA free-run (compiler per-operand lgkmcnt overlaps)
        int8v b0 = frag(Bc,            p0, p1);
        int8v b1 = frag(Bc + 1 * 2048, p0, p1);
        int8v b2 = frag(Bc + 2 * 2048, p0, p1);
        int8v b3 = frag(Bc + 3 * 2048, p0, p1);
        int8v a0 = frag(Ac,            p0, p1);
        int8v a1 = frag(Ac + 1 * 2048, p0, p1);
        int8v a2 = frag(Ac + 2 * 2048, p0, p1);
        int8v a3 = frag(Ac + 3 * 2048, p0, p1);

        __builtin_amdgcn_s_setprio(1);
        MM(a0, b0, 0, 0); MM(a0, b1, 0, 1); MM(a0, b2, 0, 2); MM(a0, b3, 0, 3);
        MM(a1, b0, 1, 0); MM(a1, b1, 1, 1); MM(a1, b2, 1, 2); MM(a1, b3, 1, 3);
        MM(a2, b0, 2, 0); MM(a2, b1, 2, 1); MM(a2, b2, 2, 2); MM(a2, b3, 2, 3);
        MM(a3, b0, 3, 0); MM(a3, b1, 3, 1); MM(a3, b2, 3, 2); MM(a3, b3, 3, 3);
        __builtin_amdgcn_s_setprio(0);

        int8v a4 = frag(Ac + 4 * 2048, p0, p1);
        int8v a5 = frag(Ac + 5 * 2048, p0, p1);
        int8v a6 = frag(Ac + 6 * 2048, p0, p1);
        int8v a7 = frag(Ac + 7 * 2048, p0, p1);

        __builtin_amdgcn_s_setprio(1);
        MM(a4, b0, 4, 0); MM(a4, b1, 4, 1); MM(a4, b2, 4, 2); MM(a4, b3, 4, 3);
        MM(a5, b0, 5, 0); MM(a5, b1, 5, 1); MM(a5, b2, 5, 2); MM(a5, b3, 5, 3);
        MM(a6, b0, 6, 0); MM(a6, b1, 6, 1); MM(a6, b2, 6, 2); MM(a6, b3, 6, 3);
        MM(a7, b0, 7, 0); MM(a7, b1, 7, 1); MM(a7, b2, 7, 2); MM(a7, b3, 7, 3);
        __builtin_amdgcn_s_setprio(0);

        __builtin_amdgcn_s_barrier();    // frees buf[cur] for t+2 staging
    }

    // Epilogue. C layout (16x16): col = lane&15, row = quad*4 + reg.
    // Per wave: 128 rows (wave_m half, mi 0..7) x 64 cols (wave_n quarter).
    const int row_base = m0 + wave_m * 128;
    const int col_base = n0 + wave_n * 64;
    const int chunk    = blockIdx.y * 4 + wave_n;   // 0..499

    // hoist targ loads (latency overlaps the max/exp work below)
    int tv[32];
#pragma unroll
    for (int mi = 0; mi < 8; ++mi)
#pragma unroll
        for (int r = 0; r < 4; ++r)
            tv[mi * 4 + r] = targ[row_base + mi * 16 + quad * 4 + r];

    // wave-wide max M (valid shift for all 128 rows of this wave tile)
    float M = acc[0][0][0];
#pragma unroll
    for (int mi = 0; mi < 8; ++mi)
#pragma unroll
        for (int ni = 0; ni < 4; ++ni)
#pragma unroll
            for (int r = 0; r < 4; ++r)
                M = fmaxf(M, acc[mi][ni][r]);
#pragma unroll
    for (int off = 1; off < 64; off <<= 1)
        M = fmaxf(M, __shfl_xor(M, off, 64));

    // all exps first (independent), then flat shuffle rounds (32-way ILP)
    float sv[32];
#pragma unroll
    for (int mi = 0; mi < 8; ++mi)
#pragma unroll
        for (int r = 0; r < 4; ++r)
            sv[mi * 4 + r] = __expf(acc[mi][0][r] - M) + __expf(acc[mi][1][r] - M) +
                             __expf(acc[mi][2][r] - M) + __expf(acc[mi][3][r] - M);
#pragma unroll
    for (int off = 1; off < 16; off <<= 1)
#pragma unroll
        for (int i = 0; i < 32; ++i)
            sv[i] += __shfl_xor(sv[i], off, 64);

    if (l16 == 0) {
#pragma unroll
        for (int mi = 0; mi < 8; ++mi)
#pragma unroll
            for (int r = 0; r < 4; ++r) {
                int row = row_base + mi * 16 + quad * 4 + r;
                partials[(size_t)row * NCHUNK + chunk] = make_float2(M, sv[mi * 4 + r]);
            }
    }

    // target gather (rare hit: ~4096/32000 of (row, col-block) pairs)
#pragma unroll
    for (int mi = 0; mi < 8; ++mi)
#pragma unroll
        for (int r = 0; r < 4; ++r) {
            int row = row_base + mi * 16 + quad * 4 + r;
            int cb  = col_base + l16;
            int t   = tv[mi * 4 + r];
            if (cb      == t) gathered[row] = acc[mi][0][r];
            if (cb + 16 == t) gathered[row] = acc[mi][1][r];
            if (cb + 32 == t) gathered[row] = acc[mi][2][r];
            if (cb + 48 == t) gathered[row] = acc[mi][3][r];
        }
}

// ------------------------------------------------------ per-row combine -----
// one wave per row; block 256 -> 4 rows/block; grid B_/4
__global__ void combine_rows(const float2* __restrict__ partials,
                             const float* __restrict__ gathered,
                             const int* __restrict__ targ,
                             const float* __restrict__ cw,
                             float* __restrict__ row_loss,
                             float* __restrict__ row_w) {
    int row  = blockIdx.x * 4 + (threadIdx.x >> 6);
    int lane = threadIdx.x & 63;
    float m = -3.0e38f, s = 0.f;
    for (int c = lane; c < NCHUNK; c += 64) {
        float2 p = partials[(size_t)row * NCHUNK + c];
        float nm = fmaxf(m, p.x);
        s = s * __expf(m - nm) + p.y * __expf(p.x - nm);
        m = nm;
    }
#pragma unroll
    for (int off = 32; off; off >>= 1) {
        float om = __shfl_xor(m, off, 64);
        float os = __shfl_xor(s, off, 64);
        float nm = fmaxf(m, om);
        s = s * __expf(m - nm) + os * __expf(om - nm);
        m = nm;
    }
    if (lane == 0) {
        float logZ = m + __logf(s);
        int t = targ[row];
        bool valid = (t != -100);
        int ts = valid ? t : 0;
        float w = valid ? cw[ts] : 0.f;
        row_loss[row] = w * (logZ - gathered[row]);
        row_w[row]    = w;
    }
}

// ---------------------------------------------------------- final reduce ----
__global__ void final_reduce(const float* __restrict__ rl,
                             const float* __restrict__ rw,
                             float* __restrict__ out) {
    __shared__ float sl[4], sw[4];
    float a = 0.f, b = 0.f;
    for (int i = threadIdx.x; i < B_; i += 256) { a += rl[i]; b += rw[i]; }
#pragma unroll
    for (int off = 32; off; off >>= 1) {
        a += __shfl_xor(a, off, 64);
        b += __shfl_xor(b, off, 64);
    }
    int w = threadIdx.x >> 6;
    if ((threadIdx.x & 63) == 0) { sl[w] = a; sw[w] = b; }
    __syncthreads();
    if (threadIdx.x == 0) {
        float ta = sl[0] + sl[1] + sl[2] + sl[3];
        float tb = sw[0] + sw[1] + sw[2] + sw[3];
        out[0] = ta / tb;
    }
}

// ------------------------------------------------------------------ launch --
extern "C" void kernel_launch(void* const* d_in, const int* in_sizes, int n_in,
                              void* d_out, int out_size, void* d_ws, size_t ws_size,
                              hipStream_t stream) {
    const float* x  = (const float*)d_in[0];   // [B_,D_]
    const float* L  = (const float*)d_in[1];   // [V_,D_]
    const int* targ = (const int*)d_in[2];     // [B_]
    const float* cw = (const float*)d_in[3];   // [V_]
    float* out = (float*)d_out;

    // workspace carve-up (all 256B-aligned)
    char* ws = (char*)d_ws;
    size_t o = 0;
    unsigned char* xq = (unsigned char*)(ws + o);  o += (size_t)B_ * D_;         // 8.4 MB
    unsigned char* Lq = (unsigned char*)(ws + o);  o += (size_t)V_ * D_;         // 65.5 MB
    float2* partials = (float2*)(ws + o);          o += (size_t)B_ * NCHUNK * 8; // 16.4 MB
    float* gathered = (float*)(ws + o);            o += (size_t)B_ * 4;
    float* row_loss = (float*)(ws + o);            o += (size_t)B_ * 4;
    float* row_w    = (float*)(ws + o);            o += (size_t)B_ * 4;
    (void)ws_size;

    // 1) fused cast (x as-is; L pre-scaled 2^6, undone by MFMA e8m0 scale 2^-6)
    cast_f32_to_fp8<<<4096, 256, 0, stream>>>(x, L, (unsigned*)xq, (unsigned*)Lq);

    // 2) fused MX-fp8 GEMM + per-tile online softmax partials
    {
        dim3 grid(B_ / BM, V_ / BN);   // (16 fast, 125 slow) -- L2 locality
        gemm_ce_partials<<<grid, 512, 0, stream>>>(xq, Lq, targ, partials, gathered);
    }

    // 3) per-row combine
    combine_rows<<<B_ / 4, 256, 0, stream>>>(partials, gathered, targ, cw, row_loss, row_w);

    // 4) final scalar
    final_reduce<<<1, 256, 0, stream>>>(row_loss, row_w, out);
}